// Round 12
// baseline (311.388 us; speedup 1.0000x reference)
//
#include <hip/hip_runtime.h>

#define NN 100000
#define NNP 100032   // padded rows; rows NN..NNP-1 of T buffers are zero
#define NE 1600000
#define NP 200000
#define NBKT 782
#define BCAP 3072
#define BKB 4096

typedef short s16x8 __attribute__((ext_vector_type(8)));
typedef float f32x4 __attribute__((ext_vector_type(4)));
typedef float f32x2 __attribute__((ext_vector_type(2)));

__device__ __forceinline__ unsigned short f2bf(float f) {  // RNE fp32->bf16
  unsigned int u = __float_as_uint(f);
  u += 0x7fffu + ((u >> 16) & 1u);
  return (unsigned short)(u >> 16);
}

// packed accumulate of one bf16 pair (lo=even ch, hi=odd ch) into f32 pair
__device__ __forceinline__ void pkadd(f32x2& a, uint u) {
  f32x2 v;
  v.x = __uint_as_float(u << 16);
  v.y = __uint_as_float(u & 0xffff0000u);
  asm("v_pk_add_f32 %0, %0, %1" : "+v"(a) : "v"(v));
}

__device__ __forceinline__ void rowadd(uint4 v, f32x2* a) {
  pkadd(a[0], v.x);
  pkadd(a[1], v.y);
  pkadd(a[2], v.z);
  pkadd(a[3], v.w);
}

// Per-group gather-sum over one CSR row. RSH = log2(row bytes): 8 for 128ch
// bf16 rows, 7 for 64ch. co = byte offset of this lane's 16B slice in the row.
// D-deep load pipeline. D=10 for k_gg targets ~60 VGPR (stay under the 64
// cliff; D=16 regressed at 76 VGPR). D=8 = R2-verified form (k_gather3).
// Tail rounds to D slots, invalid slots -> row NN (zero row). col[] may be
// over-read by up to D-1 ints past tend — lands in the Wt1 region of ws
// (mapped; values sanitized before use).
template <int RSH, int D>
__device__ __forceinline__ void gath(const int* __restrict__ col,
                                     const char* __restrict__ Tb, int s,
                                     int tend, uint co, f32x2* acc) {
  const int d = tend - s;
  const int nfull = d / D;
  const int rem = d - nfull * D;
  int e = s;
  int c[D];
#pragma unroll
  for (int j = 0; j < D; ++j) c[j] = col[e + j];
#pragma unroll 1
  for (int it = 0; it < nfull; ++it) {
    uint4 v[D];
#pragma unroll
    for (int j = 0; j < D; ++j)
      v[j] = *(const uint4*)(Tb + (((uint)c[j] << RSH) | co));
    e += D;
#pragma unroll
    for (int j = 0; j < D; ++j) c[j] = col[e + j];  // prefetch next block
#pragma unroll
    for (int j = 0; j < D; ++j) rowadd(v[j], acc);
  }
  if (rem) {
#pragma unroll
    for (int j = 0; j < D; ++j) c[j] = (j < rem) ? c[j] : NN;
    uint4 v[D];
#pragma unroll
    for (int j = 0; j < D; ++j)
      v[j] = *(const uint4*)(Tb + (((uint)c[j] << RSH) | co));
#pragma unroll
    for (int j = 0; j < D; ++j) rowadd(v[j], acc);
  }
}

// ---------------- setup: W pre-pack (gcur zeroed via hipMemsetAsync) --------
template <int NT>
__device__ __forceinline__ void prepw_dev(const float* __restrict__ W,
                                          uint* __restrict__ Wt, int tid) {
  constexpr int COUT = NT * 16;
  if (tid >= 4 * NT * 64) return;
  int lane = tid & 63, comb = tid >> 6;
  int ks = comb / NT, tl = comb % NT;
  int q = lane >> 4, n = lane & 15;
  uint w[4];
#pragma unroll
  for (int jj = 0; jj < 4; ++jj) {
    int k0 = ks * 32 + q * 8 + 2 * jj;
    uint lo = f2bf(W[k0 * COUT + tl * 16 + n]);
    uint hi = f2bf(W[(k0 + 1) * COUT + tl * 16 + n]);
    w[jj] = lo | (hi << 16);
  }
  ((uint4*)Wt)[comb * 64 + lane] = make_uint4(w[0], w[1], w[2], w[3]);
}

__global__ __launch_bounds__(256) void k_setup(const float* __restrict__ W1,
                                               const float* __restrict__ W2,
                                               const float* __restrict__ W3,
                                               uint* __restrict__ Wt1,
                                               uint* __restrict__ Wt2,
                                               uint* __restrict__ Wt3) {
  int b = blockIdx.x, t = threadIdx.x;
  if (b < 8) {
    prepw_dev<8>(W1, Wt1, b * 256 + t);
  } else if (b < 16) {
    prepw_dev<8>(W2, Wt2, (b - 8) * 256 + t);
  } else {
    prepw_dev<4>(W3, Wt3, (b - 16) * 256 + t);
  }
}

// ---------------- bucket-sort phase A ----------------
__global__ __launch_bounds__(256) void k_bucket(const int* __restrict__ ei,
                                                int* __restrict__ gcur,
                                                int* __restrict__ aux) {
  __shared__ int cnt[1024];
  __shared__ int scn[1024];
  __shared__ int cur[1024];
  __shared__ int sc[256];
  __shared__ int sorted[BKB];
  __shared__ unsigned short sbkt[BKB];
  const int t = threadIdx.x;
  const int base = blockIdx.x * BKB;

  for (int i = t; i < 1024; i += 256) cnt[i] = 0;
  __syncthreads();

  int pk[16], bk[16];
#pragma unroll
  for (int i = 0; i < 16; ++i) {
    int e = base + t + 256 * i;
    if (e < NE) {
      int src = __builtin_nontemporal_load(&ei[e]);
      int dst = __builtin_nontemporal_load(&ei[NE + e]);
      bk[i] = dst >> 7;
      pk[i] = src | ((dst & 127) << 17);
      atomicAdd(&cnt[bk[i]], 1);
    } else {
      bk[i] = -1;
    }
  }
  __syncthreads();

  int s0 = cnt[4 * t], s1 = cnt[4 * t + 1], s2 = cnt[4 * t + 2], s3 = cnt[4 * t + 3];
  int local = s0 + s1 + s2 + s3;
  sc[t] = local;
  __syncthreads();
  for (int off = 1; off < 256; off <<= 1) {
    int a = (t >= off) ? sc[t - off] : 0;
    __syncthreads();
    sc[t] += a;
    __syncthreads();
  }
  int b0 = sc[t] - local;
  scn[4 * t] = b0;
  scn[4 * t + 1] = b0 + s0;
  scn[4 * t + 2] = b0 + s0 + s1;
  scn[4 * t + 3] = b0 + s0 + s1 + s2;
  cur[4 * t] = scn[4 * t];
  cur[4 * t + 1] = scn[4 * t + 1];
  cur[4 * t + 2] = scn[4 * t + 2];
  cur[4 * t + 3] = scn[4 * t + 3];
  __syncthreads();
  const int tot = sc[255];

#pragma unroll
  for (int i = 0; i < 16; ++i) {
    if (bk[i] >= 0) {
      int pos = atomicAdd(&cur[bk[i]], 1);
      sorted[pos] = pk[i];
      sbkt[pos] = (unsigned short)bk[i];
    }
  }
  __syncthreads();

  // gcur holds RELATIVE counts; arena base is b*BCAP
  for (int b = t; b < 1024; b += 256) {
    int c = cnt[b];
    if (c > 0) cur[b] = b * BCAP + atomicAdd(&gcur[b], c);
  }
  __syncthreads();

  for (int k = t; k < tot; k += 256) {
    int b = sbkt[k];
    aux[cur[b] + (k - scn[b])] = sorted[k];
  }
}

// ---------------- merged CSR finalize ----------------
__global__ __launch_bounds__(256) void k_csr(const int* __restrict__ gcur,
                                             const int* __restrict__ aux,
                                             int* __restrict__ row_ptr,
                                             float* __restrict__ dinv,
                                             int* __restrict__ col) {
  __shared__ int red[256];
  __shared__ int c[128];
  __shared__ int cur[128];
  const int b = blockIdx.x, t = threadIdx.x;
  int p = 0;
  for (int i = t; i < b; i += 256) p += gcur[i];
  red[t] = p;
  if (t < 128) c[t] = 0;
  __syncthreads();
  for (int off = 128; off > 0; off >>= 1) {
    if (t < off) red[t] += red[t + off];
    __syncthreads();
  }
  const int base = red[0];
  const int m = gcur[b];
  const int* a = aux + (size_t)b * BCAP;
  __syncthreads();
  for (int k = t; k < m; k += 256) atomicAdd(&c[a[k] >> 17], 1);
  __syncthreads();
  int val = (t < 128) ? c[t] : 0;
  red[t] = val;
  __syncthreads();
  for (int off = 1; off < 128; off <<= 1) {
    int add = (t >= off && t < 128) ? red[t - off] : 0;
    __syncthreads();
    if (t < 128) red[t] += add;
    __syncthreads();
  }
  if (t < 128) {
    int excl = red[t] - val + base;
    int node = b * 128 + t;
    if (node < NN) {
      row_ptr[node] = excl;
      dinv[node] = rsqrtf((float)(val + 1));
      cur[t] = excl;
    }
  }
  if (b == NBKT - 1 && t == 0) row_ptr[NN] = base + m;
  __syncthreads();
  for (int k = t; k < m; k += 256) {
    int pk2 = a[k];
    int pos = atomicAdd(&cur[pk2 >> 17], 1);
    col[pos] = pk2 & 0x1FFFF;
  }
}

// ---------------- MFMA GEMM layer 1 (x fp32 -> T1 bf16) ----------------
__global__ __launch_bounds__(256) void k_gemm1(const float* __restrict__ A,
                                               const uint* __restrict__ Wt,
                                               const float* __restrict__ dinv,
                                               unsigned short* __restrict__ T) {
  constexpr int NT = 8, COUT = 128;
  __shared__ __align__(16) uint Wlds[4 * NT * 64 * 4];
  __shared__ __align__(16) unsigned short Obuf[64 * COUT];
  const int t = threadIdx.x;
  {
    const uint4* src = (const uint4*)Wt;
    uint4* dst = (uint4*)Wlds;
    for (int i = t; i < 4 * NT * 64; i += 256) dst[i] = src[i];
  }
  __syncthreads();

  const int wv = t >> 6, lane = t & 63;
  const int n = lane & 15, quad = lane >> 4;
  const int rbase = blockIdx.x * 64 + wv * 16;

  union AB { uint4 u; s16x8 s; };
  AB a[4];
  {
    int row = rbase + n;
    if (row >= NN) row = NN - 1;
    const float* ap = A + (size_t)row * 128;
#pragma unroll
    for (int ks = 0; ks < 4; ++ks) {
      float4 v0 = *(const float4*)(ap + ks * 32 + quad * 8);
      float4 v1 = *(const float4*)(ap + ks * 32 + quad * 8 + 4);
      a[ks].u.x = (uint)f2bf(v0.x) | ((uint)f2bf(v0.y) << 16);
      a[ks].u.y = (uint)f2bf(v0.z) | ((uint)f2bf(v0.w) << 16);
      a[ks].u.z = (uint)f2bf(v1.x) | ((uint)f2bf(v1.y) << 16);
      a[ks].u.w = (uint)f2bf(v1.z) | ((uint)f2bf(v1.w) << 16);
    }
  }

  f32x4 acc[NT];
#pragma unroll
  for (int tl = 0; tl < NT; ++tl) acc[tl] = (f32x4){0.f, 0.f, 0.f, 0.f};

#pragma unroll
  for (int ks = 0; ks < 4; ++ks) {
#pragma unroll
    for (int tl = 0; tl < NT; ++tl) {
      AB b;
      b.u = *(const uint4*)&Wlds[((ks * NT + tl) * 64 + lane) * 4];
      acc[tl] = __builtin_amdgcn_mfma_f32_16x16x32_bf16(a[ks].s, b.s, acc[tl], 0, 0, 0);
    }
  }

  float4 dv = *(const float4*)(dinv + rbase + quad * 4);
  float dvv[4] = {dv.x, dv.y, dv.z, dv.w};
  unsigned short* ob = Obuf + wv * 16 * COUT;
#pragma unroll
  for (int tl = 0; tl < NT; ++tl)
#pragma unroll
    for (int r = 0; r < 4; ++r)
      ob[(quad * 4 + r) * COUT + tl * 16 + n] = f2bf(acc[tl][r] * dvv[r]);

  uint4* gdst = (uint4*)(T + (size_t)rbase * COUT);
#pragma unroll
  for (int i = 0; i < 4; ++i) {
    int off16 = i * 64 + lane;
    int lrow = (off16 * 8) / COUT;
    uint4 v = make_uint4(0u, 0u, 0u, 0u);
    if (rbase + lrow < NN) v = *(const uint4*)&ob[off16 * 8];
    gdst[off16] = v;
  }
}

// ---------------- fused gather + GEMM, LOW-LDS (layers 2, 3) ----------------
// R2-verified structure: block = 16 nodes, 4 waves; one node per 16-lane
// group; D=10 load pipeline (depth probe: ~60 VGPR, +25% in-flight vs D=8);
// v_pk_add_f32 accumulate. Phase 2: 16x128 A-tile MFMA vs W streamed from
// global (L1-hot).
template <int COUT>
__global__ __launch_bounds__(256) void k_gg(const int* __restrict__ row_ptr,
                                            const int* __restrict__ col,
                                            const uint4* __restrict__ T4,
                                            const float* __restrict__ dinv,
                                            const float* __restrict__ bias,
                                            const uint4* __restrict__ Wt,
                                            unsigned short* __restrict__ Tout) {
  constexpr int NT = COUT / 16;   // 8 or 4
  constexpr int TLW = NT / 4;     // col-tiles per wave: 2 or 1
  constexpr int OSTR = COUT + 8;  // Obuf row stride (ushorts), 16B-aligned rows
  __shared__ __align__(16) uint4 Alds[16 * 17];  // 4352 B; reused as Obuf
  const int t = threadIdx.x, wv = t >> 6, lane = t & 63;
  const int nbase = blockIdx.x * 16;
  const int q = lane >> 4, cl = lane & 15;

  // ---- phase 1: one node per 16-lane group ----
  const int node = nbase + wv * 4 + q;
  int s = 0, tend = 0;
  if (node < NN) {
    s = row_ptr[node];
    tend = row_ptr[node + 1];
  }
  const char* Tb = (const char*)T4;
  const uint co = (uint)cl << 4;  // 16B slice within a 256B row
  f32x2 acc[4];
  acc[0] = (f32x2){0.f, 0.f};
  acc[1] = (f32x2){0.f, 0.f};
  acc[2] = (f32x2){0.f, 0.f};
  acc[3] = (f32x2){0.f, 0.f};
  // self-loop (node < NNP always valid; pad rows are zero)
  rowadd(*(const uint4*)(Tb + (((uint)node << 8) | co)), acc);
  gath<8, 10>(col, Tb, s, tend, co, acc);

  {
    float dv = dinv[node];  // pad nodes: finite garbage; rows zeroed at write
    float4 b0 = *(const float4*)&bias[cl * 8];
    float4 b1 = *(const float4*)&bias[cl * 8 + 4];
    float r0 = fmaxf(fmaf(dv, acc[0].x, b0.x), 0.f);
    float r1 = fmaxf(fmaf(dv, acc[0].y, b0.y), 0.f);
    float r2 = fmaxf(fmaf(dv, acc[1].x, b0.z), 0.f);
    float r3 = fmaxf(fmaf(dv, acc[1].y, b0.w), 0.f);
    float r4 = fmaxf(fmaf(dv, acc[2].x, b1.x), 0.f);
    float r5 = fmaxf(fmaf(dv, acc[2].y, b1.y), 0.f);
    float r6 = fmaxf(fmaf(dv, acc[3].x, b1.z), 0.f);
    float r7 = fmaxf(fmaf(dv, acc[3].y, b1.w), 0.f);
    uint4 o;
    o.x = (uint)f2bf(r0) | ((uint)f2bf(r1) << 16);
    o.y = (uint)f2bf(r2) | ((uint)f2bf(r3) << 16);
    o.z = (uint)f2bf(r4) | ((uint)f2bf(r5) << 16);
    o.w = (uint)f2bf(r6) | ((uint)f2bf(r7) << 16);
    Alds[(wv * 4 + q) * 17 + cl] = o;
  }
  __syncthreads();

  // ---- phase 2: 16x128 @ 128xCOUT, B-frags streamed from global (L1) ----
  const int n = lane & 15, quad = lane >> 4;
  union AB { uint4 u; s16x8 s; };
  AB a[4];
#pragma unroll
  for (int ks = 0; ks < 4; ++ks) a[ks].u = Alds[n * 17 + ks * 4 + quad];
  f32x4 acc2[TLW];
#pragma unroll
  for (int j = 0; j < TLW; ++j) acc2[j] = (f32x4){0.f, 0.f, 0.f, 0.f};
#pragma unroll
  for (int ks = 0; ks < 4; ++ks) {
#pragma unroll
    for (int j = 0; j < TLW; ++j) {
      int tl = wv * TLW + j;
      AB b;
      b.u = Wt[(ks * NT + tl) * 64 + lane];
      acc2[j] = __builtin_amdgcn_mfma_f32_16x16x32_bf16(a[ks].s, b.s, acc2[j], 0, 0, 0);
    }
  }
  __syncthreads();  // all waves done reading Alds -> safe to reuse as Obuf

  unsigned short* Obuf = (unsigned short*)Alds;
  float4 dv4 = *(const float4*)(dinv + nbase + quad * 4);
  float dvv[4] = {dv4.x, dv4.y, dv4.z, dv4.w};
#pragma unroll
  for (int j = 0; j < TLW; ++j) {
    int tl = wv * TLW + j;
#pragma unroll
    for (int r = 0; r < 4; ++r)
      Obuf[(quad * 4 + r) * OSTR + tl * 16 + n] = f2bf(acc2[j][r] * dvv[r]);
  }
  __syncthreads();

  if constexpr (COUT == 128) {
    int row = t >> 4, c16 = t & 15;
    uint4 v = make_uint4(0u, 0u, 0u, 0u);
    if (nbase + row < NN) v = *(const uint4*)&Obuf[row * OSTR + c16 * 8];
    ((uint4*)(Tout + (size_t)nbase * COUT))[row * 16 + c16] = v;
  } else {
    if (t < 128) {
      int row = t >> 3, c16 = t & 7;
      uint4 v = make_uint4(0u, 0u, 0u, 0u);
      if (nbase + row < NN) v = *(const uint4*)&Obuf[row * OSTR + c16 * 8];
      ((uint4*)(Tout + (size_t)nbase * COUT))[row * 8 + c16] = v;
    }
  }
}

// ------- gather layer 3: node-per-8-lane-group, fused dinv+b3 ---------------
// Each 8-lane group owns ONE node; its 8 lanes' 16B slices tile the full
// 128B row -> no cross-lane reduce. Fuses dinv & b3 (no relu on layer 3):
// G3 holds FINAL h3 bf16 rows; decode becomes a pure dot product.
// (R9/R11-verified form, D=8 kept for isolation of the k_gg depth probe.)
__global__ __launch_bounds__(256) void k_gather3(const int* __restrict__ row_ptr,
                                                 const int* __restrict__ col,
                                                 const uint4* __restrict__ T4,
                                                 const float* __restrict__ dinv,
                                                 const float* __restrict__ b3,
                                                 uint4* __restrict__ G3) {
  const int wid = (blockIdx.x * 256 + threadIdx.x) >> 6;
  const int lane = threadIdx.x & 63;
  const int g = lane >> 3, cl = lane & 7;
  const int node = wid * 8 + g;
  if (node >= NN) return;
  int s = row_ptr[node], tend = row_ptr[node + 1];
  const char* Tb = (const char*)T4;
  const uint co = (uint)cl << 4;  // 16B slice within a 128B row
  f32x2 acc[4];
  acc[0] = (f32x2){0.f, 0.f};
  acc[1] = (f32x2){0.f, 0.f};
  acc[2] = (f32x2){0.f, 0.f};
  acc[3] = (f32x2){0.f, 0.f};
  rowadd(*(const uint4*)(Tb + (((uint)node << 7) | co)), acc);  // self-loop
  gath<7, 8>(col, Tb, s, tend, co, acc);
  float dv = dinv[node];
  float4 bb0 = *(const float4*)&b3[cl * 8];
  float4 bb1 = *(const float4*)&b3[cl * 8 + 4];
  float h0 = fmaf(dv, acc[0].x, bb0.x);
  float h1 = fmaf(dv, acc[0].y, bb0.y);
  float h2 = fmaf(dv, acc[1].x, bb0.z);
  float h3 = fmaf(dv, acc[1].y, bb0.w);
  float h4 = fmaf(dv, acc[2].x, bb1.x);
  float h5 = fmaf(dv, acc[2].y, bb1.y);
  float h6 = fmaf(dv, acc[3].x, bb1.z);
  float h7 = fmaf(dv, acc[3].y, bb1.w);
  uint4 o;
  o.x = (uint)f2bf(h0) | ((uint)f2bf(h1) << 16);
  o.y = (uint)f2bf(h2) | ((uint)f2bf(h3) << 16);
  o.z = (uint)f2bf(h4) | ((uint)f2bf(h5) << 16);
  o.w = (uint)f2bf(h6) | ((uint)f2bf(h7) << 16);
  G3[(size_t)node * 8 + cl] = o;
}

// ---------------- pair decode: pure dot of final bf16 h3 rows ----------------
__global__ __launch_bounds__(256) void k_decode(const int* __restrict__ ni,
                                                const int* __restrict__ nj,
                                                const uint2* __restrict__ G3,
                                                float* __restrict__ out) {
  int p = blockIdx.x * 16 + (threadIdx.x >> 4);
  int cl = threadIdx.x & 15;
  int i = ni[p], j = nj[p];
  uint2 ui = G3[(size_t)i * 16 + cl];
  uint2 uj = G3[(size_t)j * 16 + cl];
  float gi0 = __uint_as_float(ui.x << 16), gi1 = __uint_as_float(ui.x & 0xffff0000u);
  float gi2 = __uint_as_float(ui.y << 16), gi3 = __uint_as_float(ui.y & 0xffff0000u);
  float gj0 = __uint_as_float(uj.x << 16), gj1 = __uint_as_float(uj.x & 0xffff0000u);
  float gj2 = __uint_as_float(uj.y << 16), gj3 = __uint_as_float(uj.y & 0xffff0000u);
  float v = gi0 * gj0 + gi1 * gj1 + gi2 * gj2 + gi3 * gj3;
  v += __shfl_xor(v, 1, 64);
  v += __shfl_xor(v, 2, 64);
  v += __shfl_xor(v, 4, 64);
  v += __shfl_xor(v, 8, 64);
  if (cl == 0) out[p] = v;
}

extern "C" void kernel_launch(void* const* d_in, const int* in_sizes, int n_in,
                              void* d_out, int out_size, void* d_ws, size_t ws_size,
                              hipStream_t stream) {
  const float* x  = (const float*)d_in[0];
  const int*   ei = (const int*)d_in[1];
  const int*   ni = (const int*)d_in[2];
  const int*   nj = (const int*)d_in[3];
  const float* W1 = (const float*)d_in[4];
  const float* b1 = (const float*)d_in[5];
  const float* W2 = (const float*)d_in[6];
  const float* b2 = (const float*)d_in[7];
  const float* W3 = (const float*)d_in[8];
  const float* b3 = (const float*)d_in[9];
  float* out = (float*)d_out;

  // ws carve (4-byte words)
  float* dinv    = (float*)d_ws;              // 102400
  int*   row_ptr = (int*)(dinv + 102400);     // 102400 (NN+1 used)
  int*   gcur    = row_ptr + 102400;          // 1024 (relative counts)
  int*   col     = gcur + 1024;               // NE (over-read <=9 ints into Wt1 is benign)
  uint*  Wt1     = (uint*)(col + NE);         // 8192
  uint*  Wt2     = Wt1 + 8192;                // 8192
  uint*  Wt3     = Wt2 + 8192;                // 4096
  uint*  Tbf     = Wt3 + 4096;                // NNP*64: T1, later T3
  uint*  T2      = Tbf + (size_t)NNP * 64;    // NNP*64
  uint*  G3      = T2 + (size_t)NNP * 64;     // NNP*32 (bf16 [NNP][64])
  int*   aux     = (int*)G3;  // 12.6 MB arena, dead before gather3 writes G3

  // ---- setup (W pre-pack; gcur via memset) + CSR build ----
  hipMemsetAsync(gcur, 0, 1024 * sizeof(int), stream);
  k_setup<<<20, 256, 0, stream>>>(W1, W2, W3, Wt1, Wt2, Wt3);
  k_bucket<<<(NE + BKB - 1) / BKB, 256, 0, stream>>>(ei, gcur, aux);
  k_csr<<<NBKT, 256, 0, stream>>>(gcur, aux, row_ptr, dinv, col);

  const int GB = NNP / 64;           // 1563
  const int FB = NNP / 16;           // 6252
  const int GATB = (NN + 31) / 32;   // 3125: 8 nodes/wave, 4 waves/block

  // layer 1 (x fp32 -> T1 bf16)
  k_gemm1<<<GB, 256, 0, stream>>>(x, Wt1, dinv, (unsigned short*)Tbf);
  // layer 2: fused gather(T1)+relu/bias(b1)+GEMM(W2)*dinv -> T2
  k_gg<128><<<FB, 256, 0, stream>>>(row_ptr, col, (const uint4*)Tbf, dinv, b1,
                                    (const uint4*)Wt2, (unsigned short*)T2);
  // layer 3: fused gather(T2)+relu/bias(b2)+GEMM(W3)*dinv -> T3 (reuses Tbf)
  k_gg<64><<<FB, 256, 0, stream>>>(row_ptr, col, (const uint4*)T2, dinv, b2,
                                   (const uint4*)Wt3, (unsigned short*)Tbf);
  // final aggregation (T3 -> G3 = final h3, bf16; dinv+b3 fused)
  k_gather3<<<GATB, 256, 0, stream>>>(row_ptr, col, (const uint4*)Tbf, dinv, b3,
                                      (uint4*)G3);
  // decode (pure dot)
  k_decode<<<NP / 16, 256, 0, stream>>>(ni, nj, (const uint2*)G3, out);
}

// Round 13
// 302.872 us; speedup vs baseline: 1.0281x; 1.0281x over previous
//
#include <hip/hip_runtime.h>

#define NN 100000
#define NNP 100032   // padded rows; rows NN..NNP-1 of T buffers are zero
#define NE 1600000
#define NP 200000
#define NBKT 782
#define BCAP 3072
#define BKB 4096

typedef short s16x8 __attribute__((ext_vector_type(8)));
typedef float f32x4 __attribute__((ext_vector_type(4)));
typedef float f32x2 __attribute__((ext_vector_type(2)));

__device__ __forceinline__ unsigned short f2bf(float f) {  // RNE fp32->bf16
  unsigned int u = __float_as_uint(f);
  u += 0x7fffu + ((u >> 16) & 1u);
  return (unsigned short)(u >> 16);
}

// packed accumulate of one bf16 pair (lo=even ch, hi=odd ch) into f32 pair
__device__ __forceinline__ void pkadd(f32x2& a, uint u) {
  f32x2 v;
  v.x = __uint_as_float(u << 16);
  v.y = __uint_as_float(u & 0xffff0000u);
  asm("v_pk_add_f32 %0, %0, %1" : "+v"(a) : "v"(v));
}

__device__ __forceinline__ void rowadd(uint4 v, f32x2* a) {
  pkadd(a[0], v.x);
  pkadd(a[1], v.y);
  pkadd(a[2], v.z);
  pkadd(a[3], v.w);
}

// Per-group gather-sum over one CSR row. RSH = log2(row bytes): 8 for 128ch
// bf16 rows, 7 for 64ch. co = byte offset of this lane's 16B slice in the row.
// 8-deep load pipeline (R2-verified form — D=10/D=16 and all structural
// alternatives regressed; per-CU miss-queue floor).
// Tail rounds to 8 slots, invalid slots -> row NN (zero row). col[] may be
// over-read by up to 7 ints past tend — lands in the Wt1 region of ws
// (mapped; values sanitized before use).
template <int RSH>
__device__ __forceinline__ void gath(const int* __restrict__ col,
                                     const char* __restrict__ Tb, int s,
                                     int tend, uint co, f32x2* acc) {
  const int d = tend - s;
  const int nfull = d >> 3;
  const int rem = d & 7;
  int e = s;
  int c[8];
#pragma unroll
  for (int j = 0; j < 8; ++j) c[j] = col[e + j];
#pragma unroll 1
  for (int it = 0; it < nfull; ++it) {
    uint4 v0 = *(const uint4*)(Tb + (((uint)c[0] << RSH) | co));
    uint4 v1 = *(const uint4*)(Tb + (((uint)c[1] << RSH) | co));
    uint4 v2 = *(const uint4*)(Tb + (((uint)c[2] << RSH) | co));
    uint4 v3 = *(const uint4*)(Tb + (((uint)c[3] << RSH) | co));
    uint4 v4 = *(const uint4*)(Tb + (((uint)c[4] << RSH) | co));
    uint4 v5 = *(const uint4*)(Tb + (((uint)c[5] << RSH) | co));
    uint4 v6 = *(const uint4*)(Tb + (((uint)c[6] << RSH) | co));
    uint4 v7 = *(const uint4*)(Tb + (((uint)c[7] << RSH) | co));
    e += 8;
#pragma unroll
    for (int j = 0; j < 8; ++j) c[j] = col[e + j];  // prefetch next block
    rowadd(v0, acc);
    rowadd(v1, acc);
    rowadd(v2, acc);
    rowadd(v3, acc);
    rowadd(v4, acc);
    rowadd(v5, acc);
    rowadd(v6, acc);
    rowadd(v7, acc);
  }
  if (rem) {
#pragma unroll
    for (int j = 0; j < 8; ++j) c[j] = (j < rem) ? c[j] : NN;
    uint4 v0 = *(const uint4*)(Tb + (((uint)c[0] << RSH) | co));
    uint4 v1 = *(const uint4*)(Tb + (((uint)c[1] << RSH) | co));
    uint4 v2 = *(const uint4*)(Tb + (((uint)c[2] << RSH) | co));
    uint4 v3 = *(const uint4*)(Tb + (((uint)c[3] << RSH) | co));
    uint4 v4 = *(const uint4*)(Tb + (((uint)c[4] << RSH) | co));
    uint4 v5 = *(const uint4*)(Tb + (((uint)c[5] << RSH) | co));
    uint4 v6 = *(const uint4*)(Tb + (((uint)c[6] << RSH) | co));
    uint4 v7 = *(const uint4*)(Tb + (((uint)c[7] << RSH) | co));
    rowadd(v0, acc);
    rowadd(v1, acc);
    rowadd(v2, acc);
    rowadd(v3, acc);
    rowadd(v4, acc);
    rowadd(v5, acc);
    rowadd(v6, acc);
    rowadd(v7, acc);
  }
}

// ---------------- setup: gcur zero + W pre-pack ----------------
template <int NT>
__device__ __forceinline__ void prepw_dev(const float* __restrict__ W,
                                          uint* __restrict__ Wt, int tid) {
  constexpr int COUT = NT * 16;
  if (tid >= 4 * NT * 64) return;
  int lane = tid & 63, comb = tid >> 6;
  int ks = comb / NT, tl = comb % NT;
  int q = lane >> 4, n = lane & 15;
  uint w[4];
#pragma unroll
  for (int jj = 0; jj < 4; ++jj) {
    int k0 = ks * 32 + q * 8 + 2 * jj;
    uint lo = f2bf(W[k0 * COUT + tl * 16 + n]);
    uint hi = f2bf(W[(k0 + 1) * COUT + tl * 16 + n]);
    w[jj] = lo | (hi << 16);
  }
  ((uint4*)Wt)[comb * 64 + lane] = make_uint4(w[0], w[1], w[2], w[3]);
}

__global__ __launch_bounds__(256) void k_setup(const float* __restrict__ W1,
                                               const float* __restrict__ W2,
                                               const float* __restrict__ W3,
                                               uint* __restrict__ Wt1,
                                               uint* __restrict__ Wt2,
                                               uint* __restrict__ Wt3,
                                               int* __restrict__ gcur) {
  int b = blockIdx.x, t = threadIdx.x;
  if (b < 4) {
    int i = b * 256 + t;
    if (i < 1024) gcur[i] = 0;
  } else if (b < 12) {
    prepw_dev<8>(W1, Wt1, (b - 4) * 256 + t);
  } else if (b < 20) {
    prepw_dev<8>(W2, Wt2, (b - 12) * 256 + t);
  } else {
    prepw_dev<4>(W3, Wt3, (b - 20) * 256 + t);
  }
}

// ---------------- bucket-sort phase A ----------------
__global__ __launch_bounds__(256) void k_bucket(const int* __restrict__ ei,
                                                int* __restrict__ gcur,
                                                int* __restrict__ aux) {
  __shared__ int cnt[1024];
  __shared__ int scn[1024];
  __shared__ int cur[1024];
  __shared__ int sc[256];
  __shared__ int sorted[BKB];
  __shared__ unsigned short sbkt[BKB];
  const int t = threadIdx.x;
  const int base = blockIdx.x * BKB;

  for (int i = t; i < 1024; i += 256) cnt[i] = 0;
  __syncthreads();

  int pk[16], bk[16];
#pragma unroll
  for (int i = 0; i < 16; ++i) {
    int e = base + t + 256 * i;
    if (e < NE) {
      int src = ei[e], dst = ei[NE + e];
      bk[i] = dst >> 7;
      pk[i] = src | ((dst & 127) << 17);
      atomicAdd(&cnt[bk[i]], 1);
    } else {
      bk[i] = -1;
    }
  }
  __syncthreads();

  int s0 = cnt[4 * t], s1 = cnt[4 * t + 1], s2 = cnt[4 * t + 2], s3 = cnt[4 * t + 3];
  int local = s0 + s1 + s2 + s3;
  sc[t] = local;
  __syncthreads();
  for (int off = 1; off < 256; off <<= 1) {
    int a = (t >= off) ? sc[t - off] : 0;
    __syncthreads();
    sc[t] += a;
    __syncthreads();
  }
  int b0 = sc[t] - local;
  scn[4 * t] = b0;
  scn[4 * t + 1] = b0 + s0;
  scn[4 * t + 2] = b0 + s0 + s1;
  scn[4 * t + 3] = b0 + s0 + s1 + s2;
  cur[4 * t] = scn[4 * t];
  cur[4 * t + 1] = scn[4 * t + 1];
  cur[4 * t + 2] = scn[4 * t + 2];
  cur[4 * t + 3] = scn[4 * t + 3];
  __syncthreads();
  const int tot = sc[255];

#pragma unroll
  for (int i = 0; i < 16; ++i) {
    if (bk[i] >= 0) {
      int pos = atomicAdd(&cur[bk[i]], 1);
      sorted[pos] = pk[i];
      sbkt[pos] = (unsigned short)bk[i];
    }
  }
  __syncthreads();

  // gcur holds RELATIVE counts; arena base is b*BCAP
  for (int b = t; b < 1024; b += 256) {
    int c = cnt[b];
    if (c > 0) cur[b] = b * BCAP + atomicAdd(&gcur[b], c);
  }
  __syncthreads();

  for (int k = t; k < tot; k += 256) {
    int b = sbkt[k];
    aux[cur[b] + (k - scn[b])] = sorted[k];
  }
}

// ---------------- merged CSR finalize ----------------
__global__ __launch_bounds__(256) void k_csr(const int* __restrict__ gcur,
                                             const int* __restrict__ aux,
                                             int* __restrict__ row_ptr,
                                             float* __restrict__ dinv,
                                             int* __restrict__ col) {
  __shared__ int red[256];
  __shared__ int c[128];
  __shared__ int cur[128];
  const int b = blockIdx.x, t = threadIdx.x;
  int p = 0;
  for (int i = t; i < b; i += 256) p += gcur[i];
  red[t] = p;
  if (t < 128) c[t] = 0;
  __syncthreads();
  for (int off = 128; off > 0; off >>= 1) {
    if (t < off) red[t] += red[t + off];
    __syncthreads();
  }
  const int base = red[0];
  const int m = gcur[b];
  const int* a = aux + (size_t)b * BCAP;
  __syncthreads();
  for (int k = t; k < m; k += 256) atomicAdd(&c[a[k] >> 17], 1);
  __syncthreads();
  int val = (t < 128) ? c[t] : 0;
  red[t] = val;
  __syncthreads();
  for (int off = 1; off < 128; off <<= 1) {
    int add = (t >= off && t < 128) ? red[t - off] : 0;
    __syncthreads();
    if (t < 128) red[t] += add;
    __syncthreads();
  }
  if (t < 128) {
    int excl = red[t] - val + base;
    int node = b * 128 + t;
    if (node < NN) {
      row_ptr[node] = excl;
      dinv[node] = rsqrtf((float)(val + 1));
      cur[t] = excl;
    }
  }
  if (b == NBKT - 1 && t == 0) row_ptr[NN] = base + m;
  __syncthreads();
  for (int k = t; k < m; k += 256) {
    int pk2 = a[k];
    int pos = atomicAdd(&cur[pk2 >> 17], 1);
    col[pos] = pk2 & 0x1FFFF;
  }
}

// ---------------- MFMA GEMM layer 1 (x fp32 -> T1 bf16) ----------------
__global__ __launch_bounds__(256) void k_gemm1(const float* __restrict__ A,
                                               const uint* __restrict__ Wt,
                                               const float* __restrict__ dinv,
                                               unsigned short* __restrict__ T) {
  constexpr int NT = 8, COUT = 128;
  __shared__ __align__(16) uint Wlds[4 * NT * 64 * 4];
  __shared__ __align__(16) unsigned short Obuf[64 * COUT];
  const int t = threadIdx.x;
  {
    const uint4* src = (const uint4*)Wt;
    uint4* dst = (uint4*)Wlds;
    for (int i = t; i < 4 * NT * 64; i += 256) dst[i] = src[i];
  }
  __syncthreads();

  const int wv = t >> 6, lane = t & 63;
  const int n = lane & 15, quad = lane >> 4;
  const int rbase = blockIdx.x * 64 + wv * 16;

  union AB { uint4 u; s16x8 s; };
  AB a[4];
  {
    int row = rbase + n;
    if (row >= NN) row = NN - 1;
    const float* ap = A + (size_t)row * 128;
#pragma unroll
    for (int ks = 0; ks < 4; ++ks) {
      float4 v0 = *(const float4*)(ap + ks * 32 + quad * 8);
      float4 v1 = *(const float4*)(ap + ks * 32 + quad * 8 + 4);
      a[ks].u.x = (uint)f2bf(v0.x) | ((uint)f2bf(v0.y) << 16);
      a[ks].u.y = (uint)f2bf(v0.z) | ((uint)f2bf(v0.w) << 16);
      a[ks].u.z = (uint)f2bf(v1.x) | ((uint)f2bf(v1.y) << 16);
      a[ks].u.w = (uint)f2bf(v1.z) | ((uint)f2bf(v1.w) << 16);
    }
  }

  f32x4 acc[NT];
#pragma unroll
  for (int tl = 0; tl < NT; ++tl) acc[tl] = (f32x4){0.f, 0.f, 0.f, 0.f};

#pragma unroll
  for (int ks = 0; ks < 4; ++ks) {
#pragma unroll
    for (int tl = 0; tl < NT; ++tl) {
      AB b;
      b.u = *(const uint4*)&Wlds[((ks * NT + tl) * 64 + lane) * 4];
      acc[tl] = __builtin_amdgcn_mfma_f32_16x16x32_bf16(a[ks].s, b.s, acc[tl], 0, 0, 0);
    }
  }

  float4 dv = *(const float4*)(dinv + rbase + quad * 4);
  float dvv[4] = {dv.x, dv.y, dv.z, dv.w};
  unsigned short* ob = Obuf + wv * 16 * COUT;
#pragma unroll
  for (int tl = 0; tl < NT; ++tl)
#pragma unroll
    for (int r = 0; r < 4; ++r)
      ob[(quad * 4 + r) * COUT + tl * 16 + n] = f2bf(acc[tl][r] * dvv[r]);

  uint4* gdst = (uint4*)(T + (size_t)rbase * COUT);
#pragma unroll
  for (int i = 0; i < 4; ++i) {
    int off16 = i * 64 + lane;
    int lrow = (off16 * 8) / COUT;
    uint4 v = make_uint4(0u, 0u, 0u, 0u);
    if (rbase + lrow < NN) v = *(const uint4*)&ob[off16 * 8];
    gdst[off16] = v;
  }
}

// ---------------- fused gather + GEMM, LOW-LDS (layers 2, 3) ----------------
// R2-verified best form: block = 16 nodes, 4 waves; one node per 16-lane
// group; 8-deep load pipeline; v_pk_add_f32 accumulate. Phase 2: 16x128
// A-tile MFMA vs W streamed from global (L1-hot).
template <int COUT>
__global__ __launch_bounds__(256) void k_gg(const int* __restrict__ row_ptr,
                                            const int* __restrict__ col,
                                            const uint4* __restrict__ T4,
                                            const float* __restrict__ dinv,
                                            const float* __restrict__ bias,
                                            const uint4* __restrict__ Wt,
                                            unsigned short* __restrict__ Tout) {
  constexpr int NT = COUT / 16;   // 8 or 4
  constexpr int TLW = NT / 4;     // col-tiles per wave: 2 or 1
  constexpr int OSTR = COUT + 8;  // Obuf row stride (ushorts), 16B-aligned rows
  __shared__ __align__(16) uint4 Alds[16 * 17];  // 4352 B; reused as Obuf
  const int t = threadIdx.x, wv = t >> 6, lane = t & 63;
  const int nbase = blockIdx.x * 16;
  const int q = lane >> 4, cl = lane & 15;

  // ---- phase 1: one node per 16-lane group ----
  const int node = nbase + wv * 4 + q;
  int s = 0, tend = 0;
  if (node < NN) {
    s = row_ptr[node];
    tend = row_ptr[node + 1];
  }
  const char* Tb = (const char*)T4;
  const uint co = (uint)cl << 4;  // 16B slice within a 256B row
  f32x2 acc[4];
  acc[0] = (f32x2){0.f, 0.f};
  acc[1] = (f32x2){0.f, 0.f};
  acc[2] = (f32x2){0.f, 0.f};
  acc[3] = (f32x2){0.f, 0.f};
  // self-loop (node < NNP always valid; pad rows are zero)
  rowadd(*(const uint4*)(Tb + (((uint)node << 8) | co)), acc);
  gath<8>(col, Tb, s, tend, co, acc);

  {
    float dv = dinv[node];  // pad nodes: finite garbage; rows zeroed at write
    float4 b0 = *(const float4*)&bias[cl * 8];
    float4 b1 = *(const float4*)&bias[cl * 8 + 4];
    float r0 = fmaxf(fmaf(dv, acc[0].x, b0.x), 0.f);
    float r1 = fmaxf(fmaf(dv, acc[0].y, b0.y), 0.f);
    float r2 = fmaxf(fmaf(dv, acc[1].x, b0.z), 0.f);
    float r3 = fmaxf(fmaf(dv, acc[1].y, b0.w), 0.f);
    float r4 = fmaxf(fmaf(dv, acc[2].x, b1.x), 0.f);
    float r5 = fmaxf(fmaf(dv, acc[2].y, b1.y), 0.f);
    float r6 = fmaxf(fmaf(dv, acc[3].x, b1.z), 0.f);
    float r7 = fmaxf(fmaf(dv, acc[3].y, b1.w), 0.f);
    uint4 o;
    o.x = (uint)f2bf(r0) | ((uint)f2bf(r1) << 16);
    o.y = (uint)f2bf(r2) | ((uint)f2bf(r3) << 16);
    o.z = (uint)f2bf(r4) | ((uint)f2bf(r5) << 16);
    o.w = (uint)f2bf(r6) | ((uint)f2bf(r7) << 16);
    Alds[(wv * 4 + q) * 17 + cl] = o;
  }
  __syncthreads();

  // ---- phase 2: 16x128 @ 128xCOUT, B-frags streamed from global (L1) ----
  const int n = lane & 15, quad = lane >> 4;
  union AB { uint4 u; s16x8 s; };
  AB a[4];
#pragma unroll
  for (int ks = 0; ks < 4; ++ks) a[ks].u = Alds[n * 17 + ks * 4 + quad];
  f32x4 acc2[TLW];
#pragma unroll
  for (int j = 0; j < TLW; ++j) acc2[j] = (f32x4){0.f, 0.f, 0.f, 0.f};
#pragma unroll
  for (int ks = 0; ks < 4; ++ks) {
#pragma unroll
    for (int j = 0; j < TLW; ++j) {
      int tl = wv * TLW + j;
      AB b;
      b.u = Wt[(ks * NT + tl) * 64 + lane];
      acc2[j] = __builtin_amdgcn_mfma_f32_16x16x32_bf16(a[ks].s, b.s, acc2[j], 0, 0, 0);
    }
  }
  __syncthreads();  // all waves done reading Alds -> safe to reuse as Obuf

  unsigned short* Obuf = (unsigned short*)Alds;
  float4 dv4 = *(const float4*)(dinv + nbase + quad * 4);
  float dvv[4] = {dv4.x, dv4.y, dv4.z, dv4.w};
#pragma unroll
  for (int j = 0; j < TLW; ++j) {
    int tl = wv * TLW + j;
#pragma unroll
    for (int r = 0; r < 4; ++r)
      Obuf[(quad * 4 + r) * OSTR + tl * 16 + n] = f2bf(acc2[j][r] * dvv[r]);
  }
  __syncthreads();

  if constexpr (COUT == 128) {
    int row = t >> 4, c16 = t & 15;
    uint4 v = make_uint4(0u, 0u, 0u, 0u);
    if (nbase + row < NN) v = *(const uint4*)&Obuf[row * OSTR + c16 * 8];
    ((uint4*)(Tout + (size_t)nbase * COUT))[row * 16 + c16] = v;
  } else {
    if (t < 128) {
      int row = t >> 3, c16 = t & 7;
      uint4 v = make_uint4(0u, 0u, 0u, 0u);
      if (nbase + row < NN) v = *(const uint4*)&Obuf[row * OSTR + c16 * 8];
      ((uint4*)(Tout + (size_t)nbase * COUT))[row * 8 + c16] = v;
    }
  }
}

// ------- gather layer 3: node-per-8-lane-group, fused dinv+b3 ---------------
// Each 8-lane group owns ONE node; its 8 lanes' 16B slices tile the full
// 128B row -> no cross-lane reduce. Fuses dinv & b3 (no relu on layer 3):
// G3 holds FINAL h3 bf16 rows; decode becomes a pure dot product.
__global__ __launch_bounds__(256) void k_gather3(const int* __restrict__ row_ptr,
                                                 const int* __restrict__ col,
                                                 const uint4* __restrict__ T4,
                                                 const float* __restrict__ dinv,
                                                 const float* __restrict__ b3,
                                                 uint4* __restrict__ G3) {
  const int wid = (blockIdx.x * 256 + threadIdx.x) >> 6;
  const int lane = threadIdx.x & 63;
  const int g = lane >> 3, cl = lane & 7;
  const int node = wid * 8 + g;
  if (node >= NN) return;
  int s = row_ptr[node], tend = row_ptr[node + 1];
  const char* Tb = (const char*)T4;
  const uint co = (uint)cl << 4;  // 16B slice within a 128B row
  f32x2 acc[4];
  acc[0] = (f32x2){0.f, 0.f};
  acc[1] = (f32x2){0.f, 0.f};
  acc[2] = (f32x2){0.f, 0.f};
  acc[3] = (f32x2){0.f, 0.f};
  rowadd(*(const uint4*)(Tb + (((uint)node << 7) | co)), acc);  // self-loop
  gath<7>(col, Tb, s, tend, co, acc);
  float dv = dinv[node];
  float4 bb0 = *(const float4*)&b3[cl * 8];
  float4 bb1 = *(const float4*)&b3[cl * 8 + 4];
  float h0 = fmaf(dv, acc[0].x, bb0.x);
  float h1 = fmaf(dv, acc[0].y, bb0.y);
  float h2 = fmaf(dv, acc[1].x, bb0.z);
  float h3 = fmaf(dv, acc[1].y, bb0.w);
  float h4 = fmaf(dv, acc[2].x, bb1.x);
  float h5 = fmaf(dv, acc[2].y, bb1.y);
  float h6 = fmaf(dv, acc[3].x, bb1.z);
  float h7 = fmaf(dv, acc[3].y, bb1.w);
  uint4 o;
  o.x = (uint)f2bf(h0) | ((uint)f2bf(h1) << 16);
  o.y = (uint)f2bf(h2) | ((uint)f2bf(h3) << 16);
  o.z = (uint)f2bf(h4) | ((uint)f2bf(h5) << 16);
  o.w = (uint)f2bf(h6) | ((uint)f2bf(h7) << 16);
  G3[(size_t)node * 8 + cl] = o;
}

// ---------------- pair decode: pure dot of final bf16 h3 rows ----------------
__global__ __launch_bounds__(256) void k_decode(const int* __restrict__ ni,
                                                const int* __restrict__ nj,
                                                const uint2* __restrict__ G3,
                                                float* __restrict__ out) {
  int p = blockIdx.x * 16 + (threadIdx.x >> 4);
  int cl = threadIdx.x & 15;
  int i = ni[p], j = nj[p];
  uint2 ui = G3[(size_t)i * 16 + cl];
  uint2 uj = G3[(size_t)j * 16 + cl];
  float gi0 = __uint_as_float(ui.x << 16), gi1 = __uint_as_float(ui.x & 0xffff0000u);
  float gi2 = __uint_as_float(ui.y << 16), gi3 = __uint_as_float(ui.y & 0xffff0000u);
  float gj0 = __uint_as_float(uj.x << 16), gj1 = __uint_as_float(uj.x & 0xffff0000u);
  float gj2 = __uint_as_float(uj.y << 16), gj3 = __uint_as_float(uj.y & 0xffff0000u);
  float v = gi0 * gj0 + gi1 * gj1 + gi2 * gj2 + gi3 * gj3;
  v += __shfl_xor(v, 1, 64);
  v += __shfl_xor(v, 2, 64);
  v += __shfl_xor(v, 4, 64);
  v += __shfl_xor(v, 8, 64);
  if (cl == 0) out[p] = v;
}

extern "C" void kernel_launch(void* const* d_in, const int* in_sizes, int n_in,
                              void* d_out, int out_size, void* d_ws, size_t ws_size,
                              hipStream_t stream) {
  const float* x  = (const float*)d_in[0];
  const int*   ei = (const int*)d_in[1];
  const int*   ni = (const int*)d_in[2];
  const int*   nj = (const int*)d_in[3];
  const float* W1 = (const float*)d_in[4];
  const float* b1 = (const float*)d_in[5];
  const float* W2 = (const float*)d_in[6];
  const float* b2 = (const float*)d_in[7];
  const float* W3 = (const float*)d_in[8];
  const float* b3 = (const float*)d_in[9];
  float* out = (float*)d_out;

  // ws carve (4-byte words)
  float* dinv    = (float*)d_ws;              // 102400
  int*   row_ptr = (int*)(dinv + 102400);     // 102400 (NN+1 used)
  int*   gcur    = row_ptr + 102400;          // 1024 (relative counts)
  int*   col     = gcur + 1024;               // NE (over-read <=7 ints into Wt1 is benign)
  uint*  Wt1     = (uint*)(col + NE);         // 8192
  uint*  Wt2     = Wt1 + 8192;                // 8192
  uint*  Wt3     = Wt2 + 8192;                // 4096
  uint*  Tbf     = Wt3 + 4096;                // NNP*64: T1, later T3
  uint*  T2      = Tbf + (size_t)NNP * 64;    // NNP*64
  uint*  G3      = T2 + (size_t)NNP * 64;     // NNP*32 (bf16 [NNP][64])
  int*   aux     = (int*)G3;  // 12.6 MB arena, dead before gather3 writes G3

  // ---- setup (gcur + weight pre-pack) + CSR build ----
  k_setup<<<24, 256, 0, stream>>>(W1, W2, W3, Wt1, Wt2, Wt3, gcur);
  k_bucket<<<(NE + BKB - 1) / BKB, 256, 0, stream>>>(ei, gcur, aux);
  k_csr<<<NBKT, 256, 0, stream>>>(gcur, aux, row_ptr, dinv, col);

  const int GB = NNP / 64;           // 1563
  const int FB = NNP / 16;           // 6252
  const int GATB = (NN + 31) / 32;   // 3125: 8 nodes/wave, 4 waves/block

  // layer 1 (x fp32 -> T1 bf16)
  k_gemm1<<<GB, 256, 0, stream>>>(x, Wt1, dinv, (unsigned short*)Tbf);
  // layer 2: fused gather(T1)+relu/bias(b1)+GEMM(W2)*dinv -> T2
  k_gg<128><<<FB, 256, 0, stream>>>(row_ptr, col, (const uint4*)Tbf, dinv, b1,
                                    (const uint4*)Wt2, (unsigned short*)T2);
  // layer 3: fused gather(T2)+relu/bias(b2)+GEMM(W3)*dinv -> T3 (reuses Tbf)
  k_gg<64><<<FB, 256, 0, stream>>>(row_ptr, col, (const uint4*)T2, dinv, b2,
                                   (const uint4*)Wt3, (unsigned short*)Tbf);
  // final aggregation (T3 -> G3 = final h3, bf16; dinv+b3 fused)
  k_gather3<<<GATB, 256, 0, stream>>>(row_ptr, col, (const uint4*)Tbf, dinv, b3,
                                      (uint4*)G3);
  // decode (pure dot)
  k_decode<<<NP / 16, 256, 0, stream>>>(ni, nj, (const uint2*)G3, out);
}